// Round 5
// baseline (215.545 us; speedup 1.0000x reference)
//
#include <hip/hip_runtime.h>
#include <hip/hip_bf16.h>

#define NXC 440
#define NYC 500
#define GCELLS (NXC * NYC)            // 220000 (NZ = 1)
#define NWORDS ((GCELLS + 31) / 32)   // 6875 bitmap words
#define MAXV 40000
#define MAXP 32
#define SCANB ((NWORDS + 255) / 256)  // 27 blocks for orred/scan

// Expected outputs are bf16-quantized but stored as fp32: round-trip.
__device__ __forceinline__ float bf16r(float x) {
    return __bfloat162float(__float2bfloat16(x));
}

// Linear cell index exactly as the numpy reference (fp32 ops). Invalid -> -1.
__device__ __forceinline__ int point_cell(const float* p) {
    float x = p[0], y = p[1], z = p[2];
    bool valid = (x >= 0.0f) && (x < 70.4f) &&
                 (y >= -40.0f) && (y < 40.0f) &&
                 (z >= -3.0f) && (z < 1.0f);
    if (!valid) return -1;
    int cx = (int)floorf(x / 0.16f);
    int cy = (int)floorf((y + 40.0f) / 0.16f);
    // z in [-3,1) -> cz == 0 always (NZ = 1)
    cx = min(max(cx, 0), NXC - 1);
    cy = min(max(cy, 0), NYC - 1);
    return cy * NXC + cx;
}

// Pass 1: per-block LDS occupancy bitmap (no global atomics) + cellid cache.
__global__ __launch_bounds__(256) void k_cell(const float* pts, int* cellid,
                                              unsigned* bitmaps, int n, int G) {
    __shared__ unsigned bm[NWORDS];   // 27.5 KB
    for (int w = threadIdx.x; w < NWORDS; w += 256) bm[w] = 0u;
    __syncthreads();
    for (int i = blockIdx.x * 256 + threadIdx.x; i < n; i += G * 256) {
        int cell = point_cell(pts + (size_t)i * 5);
        if (cellid) cellid[i] = cell;
        if (cell >= 0) atomicOr(&bm[cell >> 5], 1u << (cell & 31));
    }
    __syncthreads();
    unsigned* dst = bitmaps + (size_t)blockIdx.x * NWORDS;
    for (int w = threadIdx.x; w < NWORDS; w += 256) dst[w] = bm[w];
}

// OR-reduce the G bitmaps -> occ; per-block popcount partials; zero tickets.
__global__ __launch_bounds__(256) void k_orred(const unsigned* bitmaps, unsigned* occ,
                                               int* partials, int* ticket, int G) {
    int w = blockIdx.x * 256 + threadIdx.x;
    unsigned o = 0u;
    if (w < NWORDS) {
        for (int g = 0; g < G; ++g) o |= bitmaps[(size_t)g * NWORDS + w];
        occ[w] = o;
    }
    for (int t = blockIdx.x * 256 + threadIdx.x; t < MAXV; t += SCANB * 256) ticket[t] = 0;
    __shared__ int s[256];
    s[threadIdx.x] = (w < NWORDS) ? __popc(o) : 0;
    __syncthreads();
    for (int d = 128; d > 0; d >>= 1) {
        if (threadIdx.x < d) s[threadIdx.x] += s[threadIdx.x + d];
        __syncthreads();
    }
    if (threadIdx.x == 0) partials[blockIdx.x] = s[0];
}

// Word-level exclusive scan of popcounts -> wordprefix; emit coords for kept voxels.
__global__ __launch_bounds__(256) void k_scan(const unsigned* occ, const int* partials,
                                              int* wpre, float* out_coords) {
    int b = blockIdx.x, t = threadIdx.x;
    int w = b * 256 + t;
    unsigned o = (w < NWORDS) ? occ[w] : 0u;
    int c = __popc(o);
    __shared__ int s[256];
    s[t] = c;
    __syncthreads();
    for (int d = 1; d < 256; d <<= 1) {
        int v = (t >= d) ? s[t - d] : 0;
        __syncthreads();
        s[t] += v;
        __syncthreads();
    }
    int base = 0;
    for (int g = 0; g < b; ++g) base += partials[g];   // <=26 cached loads
    int vid = base + (s[t] - c);
    if (w < NWORDS) {
        wpre[w] = vid;
        if (vid < MAXV) {
            unsigned m = o;
            while (m) {
                int bit = __ffs(m) - 1;
                m &= m - 1u;
                if (vid < MAXV) {
                    int cell = w * 32 + bit;
                    int cy = cell / NXC, cx = cell - cy * NXC;
                    float* oc = out_coords + (size_t)vid * 3;
                    oc[0] = 0.0f;
                    oc[1] = bf16r((float)cy);
                    oc[2] = bf16r((float)cx);
                }
                ++vid;
            }
        }
    }
}

// Scatter point indices into fixed-stride per-voxel segments (kept voxels only).
__global__ __launch_bounds__(256) void k_scatter(const float* pts, const int* cellid,
                                                 const unsigned* occ, const int* wpre,
                                                 int* ticket, int* seg, int S, int n) {
    int i = blockIdx.x * 256 + threadIdx.x;
    if (i >= n) return;
    int cell = cellid ? cellid[i] : point_cell(pts + (size_t)i * 5);
    if (cell < 0) return;
    int w = cell >> 5, b = cell & 31;
    int vid = wpre[w] + __popc(occ[w] & ((1u << b) - 1u));
    if (vid >= MAXV) return;
    int t = atomicAdd(&ticket[vid], 1);
    if (t < S) seg[(size_t)vid * S + t] = i;
}

// One wave per voxel: rank by original index (stable), gather feats, write ALL
// 32 slots (zeros for empty ranks) + num_points. No output memset needed.
__global__ __launch_bounds__(256) void k_fill(const float* pts, const int* ticket,
                                              const int* seg, int S,
                                              float* out_vox, float* out_np) {
    __shared__ int slot[4][MAXP];
    int wave = threadIdx.x >> 6, lane = threadIdx.x & 63;
    int v = blockIdx.x * 4 + wave;
    if (v >= MAXV) return;
    int ntot = ticket[v];
    int nn = min(ntot, S);        // S >= 32; P(cell count > S) ~ 0
    int m = min(nn, MAXP);
    int myidx = (lane < nn) ? seg[(size_t)v * S + lane] : 0x7fffffff;
    int rank = 0;
    for (int j = 0; j < nn; ++j) {
        int ej = __shfl(myidx, j, 64);
        rank += (ej < myidx) ? 1 : 0;
    }
    if (lane < nn && rank < MAXP) slot[wave][rank] = myidx;
    // wave-private LDS; same-wave write->read is ordered (compiler waits lgkmcnt)
    if (lane < MAXP) {
        float* dst = out_vox + ((size_t)v * MAXP + lane) * 5;
        if (lane < m) {
            const float* src = pts + (size_t)slot[wave][lane] * 5;
            #pragma unroll
            for (int k = 0; k < 5; ++k) dst[k] = bf16r(src[k]);
        } else {
            #pragma unroll
            for (int k = 0; k < 5; ++k) dst[k] = 0.0f;
        }
    }
    if (lane == 0) out_np[v] = bf16r((float)m);
}

extern "C" void kernel_launch(void* const* d_in, const int* in_sizes, int n_in,
                              void* d_out, int out_size, void* d_ws, size_t ws_size,
                              hipStream_t stream) {
    const float* pts = (const float*)d_in[0];
    int n = in_sizes[0] / 5;

    float* out = (float*)d_out;   // fp32 storage, bf16-precision values
    float* out_vox    = out;                                   // MAXV*32*5
    float* out_coords = out + (size_t)MAXV * MAXP * 5;         // MAXV*3
    float* out_np     = out_coords + (size_t)MAXV * 3;         // MAXV

    // Adaptive ws layout: ints = cellid[n]? + bitmaps[G*NWORDS] + occ[NWORDS]
    //                     + wpre[NWORDS] + partials[32] + ticket[MAXV] + seg[MAXV*S]
    const size_t fixed_ints = 2 * (size_t)NWORDS + 32 + MAXV;  // 53,782
    int G = 64, S = 32; bool use_cid = false;
    {
        auto fits = [&](int g, int s, bool cid) {
            size_t ints = fixed_ints + (size_t)g * NWORDS + (size_t)MAXV * s
                        + (cid ? (size_t)n : 0);
            return ints * sizeof(int) <= ws_size;
        };
        struct Cfg { int g, s; bool cid; };
        const Cfg cfgs[] = {
            {512, 64, true}, {256, 64, true}, {256, 48, true}, {128, 48, true},
            {128, 40, false}, {64, 32, false}, {32, 32, false},
        };
        for (const Cfg& c : cfgs) {
            if (fits(c.g, c.s, c.cid)) { G = c.g; S = c.s; use_cid = c.cid; break; }
        }
    }

    int* ws = (int*)d_ws;
    int* cellid        = use_cid ? ws : nullptr;                 // n (optional)
    unsigned* bitmaps  = (unsigned*)(ws + (use_cid ? (size_t)n : 0));  // G*NWORDS
    unsigned* occ      = bitmaps + (size_t)G * NWORDS;           // NWORDS
    int* wpre          = (int*)(occ + NWORDS);                   // NWORDS
    int* partials      = wpre + NWORDS;                          // 32
    int* ticket        = partials + 32;                          // MAXV (zeroed in k_orred)
    int* seg           = ticket + MAXV;                          // MAXV * S

    int nb = (n + 255) / 256;
    k_cell<<<G, 256, 0, stream>>>(pts, cellid, bitmaps, n, G);
    k_orred<<<SCANB, 256, 0, stream>>>(bitmaps, occ, partials, ticket, G);
    k_scan<<<SCANB, 256, 0, stream>>>(occ, partials, wpre, out_coords);
    k_scatter<<<nb, 256, 0, stream>>>(pts, cellid, occ, wpre, ticket, seg, S, n);
    k_fill<<<(MAXV + 3) / 4, 256, 0, stream>>>(pts, ticket, seg, S, out_vox, out_np);
}

// Round 6
// 170.800 us; speedup vs baseline: 1.2620x; 1.2620x over previous
//
#include <hip/hip_runtime.h>
#include <hip/hip_bf16.h>

#define NXC 440
#define NYC 500
#define GCELLS (NXC * NYC)            // 220000 (NZ = 1)
#define NWORDS ((GCELLS + 31) / 32)   // 6875 bitmap words
#define MAXV 40000
#define MAXP 32
#define SCANB ((NWORDS + 255) / 256)  // 27 blocks for word-sliced kernels
#define GPB 16                        // bitmaps OR'd per k_orred block

// Expected outputs are bf16-quantized but stored as fp32: round-trip.
__device__ __forceinline__ float bf16r(float x) {
    return __bfloat162float(__float2bfloat16(x));
}

// Linear cell index exactly as the numpy reference (fp32 ops). Invalid -> -1.
__device__ __forceinline__ int point_cell(const float* p) {
    float x = p[0], y = p[1], z = p[2];
    bool valid = (x >= 0.0f) && (x < 70.4f) &&
                 (y >= -40.0f) && (y < 40.0f) &&
                 (z >= -3.0f) && (z < 1.0f);
    if (!valid) return -1;
    int cx = (int)floorf(x / 0.16f);
    int cy = (int)floorf((y + 40.0f) / 0.16f);
    // z in [-3,1) -> cz == 0 always (NZ = 1)
    cx = min(max(cx, 0), NXC - 1);
    cy = min(max(cy, 0), NYC - 1);
    return cy * NXC + cx;
}

// Pass 1: per-block LDS occupancy bitmap (no global atomics) + cellid cache.
__global__ __launch_bounds__(256) void k_cell(const float* pts, int* cellid,
                                              unsigned* bitmaps, int n, int G) {
    __shared__ unsigned bm[NWORDS];   // 27.5 KB
    for (int w = threadIdx.x; w < NWORDS; w += 256) bm[w] = 0u;
    __syncthreads();
    for (int i = blockIdx.x * 256 + threadIdx.x; i < n; i += G * 256) {
        int cell = point_cell(pts + (size_t)i * 5);
        if (cellid) cellid[i] = cell;
        if (cell >= 0) atomicOr(&bm[cell >> 5], 1u << (cell & 31));
    }
    __syncthreads();
    unsigned* dst = bitmaps + (size_t)blockIdx.x * NWORDS;
    for (int w = threadIdx.x; w < NWORDS; w += 256) dst[w] = bm[w];
}

// Parallel OR-reduce: block (bx, by) ORs bitmaps [by*GPB, by*GPB+GPB) over its
// 256-word slice, one atomicOr per word into occ (pre-zeroed by memset).
__global__ __launch_bounds__(256) void k_orred(const unsigned* bitmaps, unsigned* occ) {
    int w = blockIdx.x * 256 + threadIdx.x;
    if (w >= NWORDS) return;
    const unsigned* src = bitmaps + (size_t)blockIdx.y * GPB * NWORDS + w;
    unsigned o = 0u;
    #pragma unroll
    for (int g = 0; g < GPB; ++g) o |= src[(size_t)g * NWORDS];
    if (o) atomicOr(&occ[w], o);
}

// Per-SCANB-block popcount partials of the final occ bitmap.
__global__ __launch_bounds__(256) void k_partials(const unsigned* occ, int* partials) {
    int w = blockIdx.x * 256 + threadIdx.x;
    __shared__ int s[256];
    s[threadIdx.x] = (w < NWORDS) ? __popc(occ[w]) : 0;
    __syncthreads();
    for (int d = 128; d > 0; d >>= 1) {
        if (threadIdx.x < d) s[threadIdx.x] += s[threadIdx.x + d];
        __syncthreads();
    }
    if (threadIdx.x == 0) partials[blockIdx.x] = s[0];
}

// Word-level exclusive scan of popcounts -> wordprefix; emit coords for kept voxels.
__global__ __launch_bounds__(256) void k_scan(const unsigned* occ, const int* partials,
                                              int* wpre, float* out_coords) {
    int b = blockIdx.x, t = threadIdx.x;
    int w = b * 256 + t;
    unsigned o = (w < NWORDS) ? occ[w] : 0u;
    int c = __popc(o);
    __shared__ int s[256];
    s[t] = c;
    __syncthreads();
    for (int d = 1; d < 256; d <<= 1) {
        int v = (t >= d) ? s[t - d] : 0;
        __syncthreads();
        s[t] += v;
        __syncthreads();
    }
    int base = 0;
    for (int g = 0; g < b; ++g) base += partials[g];   // <=26 cached loads
    int vid = base + (s[t] - c);
    if (w < NWORDS) {
        wpre[w] = vid;
        if (vid < MAXV) {
            unsigned m = o;
            while (m) {
                int bit = __ffs(m) - 1;
                m &= m - 1u;
                if (vid < MAXV) {
                    int cell = w * 32 + bit;
                    int cy = cell / NXC, cx = cell - cy * NXC;
                    float* oc = out_coords + (size_t)vid * 3;
                    oc[0] = 0.0f;
                    oc[1] = bf16r((float)cy);
                    oc[2] = bf16r((float)cx);
                }
                ++vid;
            }
        }
    }
}

// Scatter point indices into fixed-stride per-voxel segments (kept voxels only).
__global__ __launch_bounds__(256) void k_scatter(const float* pts, const int* cellid,
                                                 const unsigned* occ, const int* wpre,
                                                 int* ticket, int* seg, int S, int n) {
    int i = blockIdx.x * 256 + threadIdx.x;
    if (i >= n) return;
    int cell = cellid ? cellid[i] : point_cell(pts + (size_t)i * 5);
    if (cell < 0) return;
    int w = cell >> 5, b = cell & 31;
    int vid = wpre[w] + __popc(occ[w] & ((1u << b) - 1u));
    if (vid >= MAXV) return;
    int t = atomicAdd(&ticket[vid], 1);
    if (t < S) seg[(size_t)vid * S + t] = i;
}

// One wave per voxel: rank by original index (stable), gather feats, write ALL
// 32 slots (zeros for empty ranks) + num_points. No output memset needed.
__global__ __launch_bounds__(256) void k_fill(const float* pts, const int* ticket,
                                              const int* seg, int S,
                                              float* out_vox, float* out_np) {
    __shared__ int slot[4][MAXP];
    int wave = threadIdx.x >> 6, lane = threadIdx.x & 63;
    int v = blockIdx.x * 4 + wave;     // MAXV % 4 == 0 -> always in range
    int ntot = ticket[v];
    int nn = min(ntot, S);             // S >= 32; P(cell count > S) ~ 0
    int m = min(nn, MAXP);
    int myidx = (lane < nn) ? seg[(size_t)v * S + lane] : 0x7fffffff;
    int rank = 0;
    for (int j = 0; j < nn; ++j) {
        int ej = __shfl(myidx, j, 64);
        rank += (ej < myidx) ? 1 : 0;
    }
    if (lane < nn && rank < MAXP) slot[wave][rank] = myidx;
    __syncthreads();   // order LDS scatter before readback (all threads reach)
    if (lane < MAXP) {
        float* dst = out_vox + ((size_t)v * MAXP + lane) * 5;
        if (lane < m) {
            const float* src = pts + (size_t)slot[wave][lane] * 5;
            #pragma unroll
            for (int k = 0; k < 5; ++k) dst[k] = bf16r(src[k]);
        } else {
            #pragma unroll
            for (int k = 0; k < 5; ++k) dst[k] = 0.0f;
        }
    }
    if (lane == 0) out_np[v] = bf16r((float)m);
}

extern "C" void kernel_launch(void* const* d_in, const int* in_sizes, int n_in,
                              void* d_out, int out_size, void* d_ws, size_t ws_size,
                              hipStream_t stream) {
    const float* pts = (const float*)d_in[0];
    int n = in_sizes[0] / 5;

    float* out = (float*)d_out;   // fp32 storage, bf16-precision values
    float* out_vox    = out;                                   // MAXV*32*5
    float* out_coords = out + (size_t)MAXV * MAXP * 5;         // MAXV*3
    float* out_np     = out_coords + (size_t)MAXV * 3;         // MAXV

    // ws ints: cellid[n]? + bitmaps[G*NWORDS] + occ[NWORDS] + ticket[MAXV]
    //          + wpre[NWORDS] + partials[32] + seg[MAXV*S]
    const size_t fixed_ints = 2 * (size_t)NWORDS + 32 + MAXV;  // 53,782
    int G = 64, S = 32; bool use_cid = false;
    {
        auto fits = [&](int g, int s, bool cid) {
            size_t ints = fixed_ints + (size_t)g * NWORDS + (size_t)MAXV * s
                        + (cid ? (size_t)n : 0);
            return ints * sizeof(int) <= ws_size;
        };
        struct Cfg { int g, s; bool cid; };
        const Cfg cfgs[] = {
            {512, 64, true}, {256, 64, true}, {256, 48, true}, {128, 48, true},
            {128, 40, false}, {64, 32, false}, {32, 32, false},
        };
        for (const Cfg& c : cfgs) {
            if (fits(c.g, c.s, c.cid)) { G = c.g; S = c.s; use_cid = c.cid; break; }
        }
    }

    int* ws = (int*)d_ws;
    int* cellid        = use_cid ? ws : nullptr;                       // n (optional)
    unsigned* bitmaps  = (unsigned*)(ws + (use_cid ? (size_t)n : 0));  // G*NWORDS
    unsigned* occ      = bitmaps + (size_t)G * NWORDS;                 // NWORDS  (zeroed)
    int* ticket        = (int*)(occ + NWORDS);                         // MAXV    (zeroed)
    int* wpre          = ticket + MAXV;                                // NWORDS
    int* partials      = wpre + NWORDS;                                // 32
    int* seg           = partials + 32;                                // MAXV * S

    // Zero occ + ticket (contiguous, 187 KB).
    hipMemsetAsync(occ, 0, (size_t)(NWORDS + MAXV) * sizeof(int), stream);

    int nb = (n + 255) / 256;
    k_cell<<<G, 256, 0, stream>>>(pts, cellid, bitmaps, n, G);
    k_orred<<<dim3(SCANB, G / GPB), 256, 0, stream>>>(bitmaps, occ);
    k_partials<<<SCANB, 256, 0, stream>>>(occ, partials);
    k_scan<<<SCANB, 256, 0, stream>>>(occ, partials, wpre, out_coords);
    k_scatter<<<nb, 256, 0, stream>>>(pts, cellid, occ, wpre, ticket, seg, S, n);
    k_fill<<<(MAXV + 3) / 4, 256, 0, stream>>>(pts, ticket, seg, S, out_vox, out_np);
}

// Round 7
// 150.691 us; speedup vs baseline: 1.4304x; 1.1334x over previous
//
#include <hip/hip_runtime.h>
#include <hip/hip_bf16.h>

#define NXC 440
#define NYC 500
#define GCELLS (NXC * NYC)            // 220000 (NZ = 1)
#define NWORDS ((GCELLS + 31) / 32)   // 6875 bitmap words
#define MAXV 40000
#define MAXP 32
#define SCANB ((NWORDS + 255) / 256)  // 27 blocks for word-sliced kernels
#define GPB 16                        // bitmaps OR'd per k_orred block
#define TPAD 16                       // ticket stride (ints): 1 counter / 64B line

// Expected outputs are bf16-quantized but stored as fp32: round-trip.
__device__ __forceinline__ float bf16r(float x) {
    return __bfloat162float(__float2bfloat16(x));
}

// Linear cell index exactly as the numpy reference (fp32 ops). Invalid -> -1.
__device__ __forceinline__ int point_cell(const float* p) {
    float x = p[0], y = p[1], z = p[2];
    bool valid = (x >= 0.0f) && (x < 70.4f) &&
                 (y >= -40.0f) && (y < 40.0f) &&
                 (z >= -3.0f) && (z < 1.0f);
    if (!valid) return -1;
    int cx = (int)floorf(x / 0.16f);
    int cy = (int)floorf((y + 40.0f) / 0.16f);
    // z in [-3,1) -> cz == 0 always (NZ = 1)
    cx = min(max(cx, 0), NXC - 1);
    cy = min(max(cy, 0), NYC - 1);
    return cy * NXC + cx;
}

// Pass 1: per-block LDS occupancy bitmap (no global atomics) + cellid cache.
__global__ __launch_bounds__(256) void k_cell(const float* pts, int* cellid,
                                              unsigned* bitmaps, int n, int G) {
    __shared__ unsigned bm[NWORDS];   // 27.5 KB
    for (int w = threadIdx.x; w < NWORDS; w += 256) bm[w] = 0u;
    __syncthreads();
    for (int i = blockIdx.x * 256 + threadIdx.x; i < n; i += G * 256) {
        int cell = point_cell(pts + (size_t)i * 5);
        if (cellid) cellid[i] = cell;
        if (cell >= 0) atomicOr(&bm[cell >> 5], 1u << (cell & 31));
    }
    __syncthreads();
    unsigned* dst = bitmaps + (size_t)blockIdx.x * NWORDS;
    for (int w = threadIdx.x; w < NWORDS; w += 256) dst[w] = bm[w];
}

// Parallel OR-reduce: block (bx, by) ORs bitmaps [by*GPB, by*GPB+GPB) over its
// 256-word slice, one atomicOr per word into occ (pre-zeroed by memset).
__global__ __launch_bounds__(256) void k_orred(const unsigned* bitmaps, unsigned* occ) {
    int w = blockIdx.x * 256 + threadIdx.x;
    if (w >= NWORDS) return;
    const unsigned* src = bitmaps + (size_t)blockIdx.y * GPB * NWORDS + w;
    unsigned o = 0u;
    #pragma unroll
    for (int g = 0; g < GPB; ++g) o |= src[(size_t)g * NWORDS];
    if (o) atomicOr(&occ[w], o);
}

// Per-SCANB-block popcount partials of the final occ bitmap.
__global__ __launch_bounds__(256) void k_partials(const unsigned* occ, int* partials) {
    int w = blockIdx.x * 256 + threadIdx.x;
    __shared__ int s[256];
    s[threadIdx.x] = (w < NWORDS) ? __popc(occ[w]) : 0;
    __syncthreads();
    for (int d = 128; d > 0; d >>= 1) {
        if (threadIdx.x < d) s[threadIdx.x] += s[threadIdx.x + d];
        __syncthreads();
    }
    if (threadIdx.x == 0) partials[blockIdx.x] = s[0];
}

// Word-level exclusive scan of popcounts -> wordprefix; emit coords for kept voxels.
__global__ __launch_bounds__(256) void k_scan(const unsigned* occ, const int* partials,
                                              int* wpre, float* out_coords) {
    int b = blockIdx.x, t = threadIdx.x;
    int w = b * 256 + t;
    unsigned o = (w < NWORDS) ? occ[w] : 0u;
    int c = __popc(o);
    __shared__ int s[256];
    s[t] = c;
    __syncthreads();
    for (int d = 1; d < 256; d <<= 1) {
        int v = (t >= d) ? s[t - d] : 0;
        __syncthreads();
        s[t] += v;
        __syncthreads();
    }
    int base = 0;
    for (int g = 0; g < b; ++g) base += partials[g];   // <=26 cached loads
    int vid = base + (s[t] - c);
    if (w < NWORDS) {
        wpre[w] = vid;
        if (vid < MAXV) {
            unsigned m = o;
            while (m) {
                int bit = __ffs(m) - 1;
                m &= m - 1u;
                if (vid < MAXV) {
                    int cell = w * 32 + bit;
                    int cy = cell / NXC, cx = cell - cy * NXC;
                    float* oc = out_coords + (size_t)vid * 3;
                    oc[0] = 0.0f;
                    oc[1] = bf16r((float)cy);
                    oc[2] = bf16r((float)cx);
                }
                ++vid;
            }
        }
    }
}

// Scatter point indices into fixed-stride per-voxel segments (kept voxels only).
// ticket is padded to 1 counter per 64B line: kills cross-XCD false sharing.
__global__ __launch_bounds__(256) void k_scatter(const float* pts, const int* cellid,
                                                 const unsigned* occ, const int* wpre,
                                                 int* ticket, int* seg, int S, int n) {
    int i = blockIdx.x * 256 + threadIdx.x;
    if (i >= n) return;
    int cell = cellid ? cellid[i] : point_cell(pts + (size_t)i * 5);
    if (cell < 0) return;
    int w = cell >> 5, b = cell & 31;
    int vid = wpre[w] + __popc(occ[w] & ((1u << b) - 1u));
    if (vid >= MAXV) return;
    int t = atomicAdd(&ticket[(size_t)vid * TPAD], 1);
    if (t < S) seg[(size_t)vid * S + t] = i;
}

// One wave per voxel: rank by original index (stable), gather feats, write ALL
// 32 slots (zeros for empty ranks) + num_points. No output memset needed.
__global__ __launch_bounds__(256) void k_fill(const float* pts, const int* ticket,
                                              const int* seg, int S,
                                              float* out_vox, float* out_np) {
    __shared__ int slot[4][MAXP];
    int wave = threadIdx.x >> 6, lane = threadIdx.x & 63;
    int v = blockIdx.x * 4 + wave;     // MAXV % 4 == 0 -> always in range
    int ntot = ticket[(size_t)v * TPAD];
    int nn = min(ntot, S);             // S >= 32; P(cell count > S) ~ 0
    int m = min(nn, MAXP);
    int myidx = (lane < nn) ? seg[(size_t)v * S + lane] : 0x7fffffff;
    int rank = 0;
    for (int j = 0; j < nn; ++j) {
        int ej = __shfl(myidx, j, 64);
        rank += (ej < myidx) ? 1 : 0;
    }
    if (lane < nn && rank < MAXP) slot[wave][rank] = myidx;
    __syncthreads();   // order LDS scatter before readback (all threads reach)
    if (lane < MAXP) {
        float* dst = out_vox + ((size_t)v * MAXP + lane) * 5;
        if (lane < m) {
            const float* src = pts + (size_t)slot[wave][lane] * 5;
            #pragma unroll
            for (int k = 0; k < 5; ++k) dst[k] = bf16r(src[k]);
        } else {
            #pragma unroll
            for (int k = 0; k < 5; ++k) dst[k] = 0.0f;
        }
    }
    if (lane == 0) out_np[v] = bf16r((float)m);
}

extern "C" void kernel_launch(void* const* d_in, const int* in_sizes, int n_in,
                              void* d_out, int out_size, void* d_ws, size_t ws_size,
                              hipStream_t stream) {
    const float* pts = (const float*)d_in[0];
    int n = in_sizes[0] / 5;

    float* out = (float*)d_out;   // fp32 storage, bf16-precision values
    float* out_vox    = out;                                   // MAXV*32*5
    float* out_coords = out + (size_t)MAXV * MAXP * 5;         // MAXV*3
    float* out_np     = out_coords + (size_t)MAXV * 3;         // MAXV

    // ws ints: cellid[n]? + bitmaps[G*NWORDS] + occ[NWORDS] + ticket[MAXV*TPAD]
    //          + wpre[NWORDS] + partials[32] + seg[MAXV*S]
    const size_t fixed_ints = 2 * (size_t)NWORDS + 32 + (size_t)MAXV * TPAD;
    int G = 64, S = 32; bool use_cid = false;
    {
        auto fits = [&](int g, int s, bool cid) {
            size_t ints = fixed_ints + (size_t)g * NWORDS + (size_t)MAXV * s
                        + (cid ? (size_t)n : 0);
            return ints * sizeof(int) <= ws_size;
        };
        struct Cfg { int g, s; bool cid; };
        const Cfg cfgs[] = {
            {512, 64, true}, {256, 64, true}, {256, 48, true}, {128, 48, true},
            {128, 40, false}, {64, 32, false}, {32, 32, false},
        };
        for (const Cfg& c : cfgs) {
            if (fits(c.g, c.s, c.cid)) { G = c.g; S = c.s; use_cid = c.cid; break; }
        }
    }

    int* ws = (int*)d_ws;
    int* cellid        = use_cid ? ws : nullptr;                       // n (optional)
    unsigned* bitmaps  = (unsigned*)(ws + (use_cid ? (size_t)n : 0));  // G*NWORDS
    unsigned* occ      = bitmaps + (size_t)G * NWORDS;                 // NWORDS (zeroed)
    int* ticket        = (int*)(occ + NWORDS);                         // MAXV*TPAD (zeroed)
    int* wpre          = ticket + (size_t)MAXV * TPAD;                 // NWORDS
    int* partials      = wpre + NWORDS;                                // 32
    int* seg           = partials + 32;                                // MAXV * S

    // Zero occ + padded tickets (contiguous, 2.6 MB).
    hipMemsetAsync(occ, 0, ((size_t)NWORDS + (size_t)MAXV * TPAD) * sizeof(int), stream);

    int nb = (n + 255) / 256;
    k_cell<<<G, 256, 0, stream>>>(pts, cellid, bitmaps, n, G);
    k_orred<<<dim3(SCANB, G / GPB), 256, 0, stream>>>(bitmaps, occ);
    k_partials<<<SCANB, 256, 0, stream>>>(occ, partials);
    k_scan<<<SCANB, 256, 0, stream>>>(occ, partials, wpre, out_coords);
    k_scatter<<<nb, 256, 0, stream>>>(pts, cellid, occ, wpre, ticket, seg, S, n);
    k_fill<<<(MAXV + 3) / 4, 256, 0, stream>>>(pts, ticket, seg, S, out_vox, out_np);
}